// Round 4
// baseline (520.629 us; speedup 1.0000x reference)
//
#include <hip/hip_runtime.h>
#include <math.h>

#define T_TOK 16384
#define HID   4096
#define NEXP  64
#define WHALF ((size_t)NEXP * HID)

typedef __attribute__((ext_vector_type(8))) short short8;
typedef __attribute__((ext_vector_type(4))) float float4v;

__device__ __forceinline__ unsigned short rne_bf16(float f) {
  unsigned u = __float_as_uint(f);
  unsigned r = u + 0x7FFFu + ((u >> 16) & 1u);
  return (unsigned short)(r >> 16);
}
__device__ __forceinline__ float bf16_f(unsigned short h) {
  return __uint_as_float(((unsigned)h) << 16);
}

// 3-way bf16 split of w: f = hi+mid+lo + O(2^-26 |f|).
__global__ void w_convert3(const float* __restrict__ w,
                           unsigned short* __restrict__ wh,
                           unsigned short* __restrict__ wm,
                           unsigned short* __restrict__ wl) {
  int t = blockIdx.x * 256 + threadIdx.x;
#pragma unroll
  for (int j = 0; j < 4; ++j) {
    int idx = t + j * 65536;
    float f = w[idx];
    unsigned short h = rne_bf16(f);
    float r1 = f - bf16_f(h);
    unsigned short m = rne_bf16(r1);
    float r2 = r1 - bf16_f(m);
    wh[idx] = h; wm[idx] = m; wl[idx] = rne_bf16(r2);
  }
}

// Occupancy-first GEMM: wave = 32 tokens x 64 experts x KRANGE. KS=8 gives
// 4096 waves = 4 waves/SIMD (matches launch_bounds cap of 128 VGPR); latency
// hidden by waves, not deep register pipelines (R3 showed the compiler sinks
// those). Distance-1 A prefetch only.
template <int KS>
__global__ __launch_bounds__(256, 4)
void router_gemm(const float* __restrict__ x,
                 const unsigned short* __restrict__ wh,
                 const unsigned short* __restrict__ wm,
                 const unsigned short* __restrict__ wl,
                 float* __restrict__ partial) {
  constexpr int KRANGE = HID / KS;
  constexpr int NCH = KRANGE / 32;
  const int lane = threadIdx.x & 63;
  const int wid  = threadIdx.x >> 6;
  const int W    = blockIdx.x * 4 + wid;
  const int ks   = W & (KS - 1);
  const int t0   = (W / KS) * 32;
  const int r    = lane & 15;
  const int q    = lane >> 4;
  const int k0   = ks * KRANGE + q * 8;

  const float* pa0 = x + (size_t)(t0 + r) * HID + k0;
  const float* pa1 = pa0 + (size_t)16 * HID;
  const unsigned short* pb[3];
  pb[0] = wh + (size_t)r * HID + k0;
  pb[1] = wm + (size_t)r * HID + k0;
  pb[2] = wl + (size_t)r * HID + k0;

  float4v acc[2][4];
#pragma unroll
  for (int m = 0; m < 2; ++m)
#pragma unroll
    for (int n = 0; n < 4; ++n) acc[m][n] = (float4v)(0.f);

  float4 araw[2][2][2];     // [buf][Mtile][half-of-8]
  short8 ah[2], am_[2], al[2];
  short8 Bb[2][2][3];       // [half][n_local][split]

#define LOADA(buf, c) do {                                                   \
    const int _o = (c) * 32;                                                 \
    araw[buf][0][0] = *(const float4*)(pa0 + _o);                            \
    araw[buf][0][1] = *(const float4*)(pa0 + _o + 4);                        \
    araw[buf][1][0] = *(const float4*)(pa1 + _o);                            \
    araw[buf][1][1] = *(const float4*)(pa1 + _o + 4);                        \
  } while (0)

#define LOADB(half, c) do {                                                  \
    const int _o = (c) * 32;                                                 \
    _Pragma("unroll")                                                        \
    for (int _nl = 0; _nl < 2; ++_nl) {                                      \
      const size_t _nb = (size_t)((half) * 2 + _nl) * 16 * HID + _o;         \
      _Pragma("unroll")                                                      \
      for (int _s = 0; _s < 3; ++_s)                                         \
        Bb[half][_nl][_s] = *(const short8*)(pb[_s] + _nb);                  \
    }                                                                        \
  } while (0)

#define SPLITA(buf) do {                                                     \
    _Pragma("unroll")                                                        \
    for (int _m = 0; _m < 2; ++_m) {                                         \
      const float4 _v0 = araw[buf][_m][0], _v1 = araw[buf][_m][1];           \
      float _f[8] = {_v0.x,_v0.y,_v0.z,_v0.w,_v1.x,_v1.y,_v1.z,_v1.w};       \
      _Pragma("unroll")                                                      \
      for (int _j = 0; _j < 8; ++_j) {                                       \
        unsigned short _h = rne_bf16(_f[_j]);                                \
        float _r1 = _f[_j] - bf16_f(_h);                                     \
        unsigned short _mm = rne_bf16(_r1);                                  \
        float _r2 = _r1 - bf16_f(_mm);                                       \
        ah[_m][_j] = (short)_h; am_[_m][_j] = (short)_mm;                    \
        al[_m][_j] = (short)rne_bf16(_r2);                                   \
      }                                                                      \
    }                                                                        \
  } while (0)

#define MFMAH(half) do {                                                     \
    _Pragma("unroll")                                                        \
    for (int _nl = 0; _nl < 2; ++_nl) {                                      \
      const int _n = (half) * 2 + _nl;                                       \
      const short8 _BH = Bb[half][_nl][0];                                   \
      const short8 _BM = Bb[half][_nl][1];                                   \
      const short8 _BL = Bb[half][_nl][2];                                   \
      _Pragma("unroll")                                                      \
      for (int _m = 0; _m < 2; ++_m) {                                       \
        float4v _a = acc[_m][_n];                                            \
        _a = __builtin_amdgcn_mfma_f32_16x16x32_bf16(al[_m],  _BH, _a,0,0,0);\
        _a = __builtin_amdgcn_mfma_f32_16x16x32_bf16(ah[_m],  _BL, _a,0,0,0);\
        _a = __builtin_amdgcn_mfma_f32_16x16x32_bf16(am_[_m], _BM, _a,0,0,0);\
        _a = __builtin_amdgcn_mfma_f32_16x16x32_bf16(am_[_m], _BH, _a,0,0,0);\
        _a = __builtin_amdgcn_mfma_f32_16x16x32_bf16(ah[_m],  _BM, _a,0,0,0);\
        _a = __builtin_amdgcn_mfma_f32_16x16x32_bf16(ah[_m],  _BH, _a,0,0,0);\
        acc[_m][_n] = _a;                                                    \
      }                                                                      \
    }                                                                        \
  } while (0)

  LOADA(0, 0);
  LOADB(0, 0);
  for (int c = 0; c < NCH; ++c) {
    const int cb = c & 1, nb = cb ^ 1;
    if (c + 1 < NCH) LOADA(nb, c + 1);
    SPLITA(cb);
    LOADB(1, c);
    MFMAH(0);
    if (c + 1 < NCH) LOADB(0, c + 1);
    MFMAH(1);
  }
#undef LOADA
#undef LOADB
#undef SPLITA
#undef MFMAH

  // D[row=(lane>>4)*4+reg][col=lane&15]  (m89/m91-verified)
  float* po = partial + ((size_t)ks * T_TOK + t0) * NEXP;
#pragma unroll
  for (int m = 0; m < 2; ++m)
#pragma unroll
    for (int n = 0; n < 4; ++n)
#pragma unroll
      for (int rr = 0; rr < 4; ++rr)
        po[(size_t)(m * 16 + q * 4 + rr) * NEXP + n * 16 + r] = acc[m][n][rr];
}

// topk v2: 8 lanes per token (wave = 8 tokens). Each lane owns 8 experts,
// maintains a local argmax; 8 extractions of a 3-step 8-lane butterfly.
// All register indices static (no scratch). Softmax denominator over the
// full 64 cancels in the renorm, so only the 8 winners matter.
template <int KS>
__global__ __launch_bounds__(256)
void router_topk(const float* __restrict__ partial,
                 float* __restrict__ logits_out,
                 float* __restrict__ scores_out,
                 float* __restrict__ idx_out) {
  const int lane = threadIdx.x & 63;
  const int wid  = threadIdx.x >> 6;
  const int g    = lane >> 3;   // token group within wave
  const int j    = lane & 7;    // lane within group
  const int t    = blockIdx.x * 32 + wid * 8 + g;

  const float* pp = partial + (size_t)t * NEXP + j * 8;
  float4v a0 = (float4v)(0.f), a1 = (float4v)(0.f);
#pragma unroll
  for (int s = 0; s < KS; ++s) {
    const float4v* p4 = (const float4v*)(pp + (size_t)s * T_TOK * NEXP);
    a0 += p4[0];
    a1 += p4[1];
  }
  float4v* lo = (float4v*)(logits_out + (size_t)t * NEXP + j * 8);
  lo[0] = a0; lo[1] = a1;   // wave writes 2KB contiguous

  float v[8] = {a0[0], a0[1], a0[2], a0[3], a1[0], a1[1], a1[2], a1[3]};
  float lv = v[0]; int li = 0;
#pragma unroll
  for (int i = 1; i < 8; ++i) {
    bool b = v[i] > lv;               // strict: ties keep lower index
    lv = b ? v[i] : lv; li = b ? i : li;
  }

  float win_v = 0.f; int win_i = 0;
#pragma unroll
  for (int k = 0; k < 8; ++k) {
    float bv = lv; int bi = j * 8 + li;
#pragma unroll
    for (int off = 1; off <= 4; off <<= 1) {
      float ov = __shfl_xor(bv, off, 64);
      int   oi = __shfl_xor(bi, off, 64);
      if (ov > bv || (ov == bv && oi < bi)) { bv = ov; bi = oi; }
    }
    if (j == k) { win_v = bv; win_i = bi; }
    const bool own = (bi >> 3) == j;
    const int  sl  = bi & 7;
#pragma unroll
    for (int i = 0; i < 8; ++i)
      if (own && sl == i) v[i] = -INFINITY;
    lv = v[0]; li = 0;
#pragma unroll
    for (int i = 1; i < 8; ++i) {
      bool b = v[i] > lv;
      lv = b ? v[i] : lv; li = b ? i : li;
    }
  }

  float mx = __shfl(win_v, lane & 56, 64);   // rank-0 = group max
  float p  = __expf(win_v - mx);
  float ssum = p;
#pragma unroll
  for (int off = 1; off <= 4; off <<= 1) ssum += __shfl_xor(ssum, off, 64);

  scores_out[(size_t)t * 8 + j] = p / ssum;
  idx_out[(size_t)t * 8 + j]    = (float)win_i;
}

extern "C" void kernel_launch(void* const* d_in, const int* in_sizes, int n_in,
                              void* d_out, int out_size, void* d_ws, size_t ws_size,
                              hipStream_t stream) {
  const float* x = (const float*)d_in[0];   // [16384, 4096]
  const float* w = (const float*)d_in[1];   // [64, 4096]
  float* out    = (float*)d_out;
  float* logits = out;                                   // [T,64]
  float* scores = out + (size_t)T_TOK * NEXP;            // [T,8]
  float* idxo   = scores + (size_t)T_TOK * 8;            // [T,8]

  const size_t need8 = (size_t)8 * T_TOK * NEXP * sizeof(float) + 3 * WHALF * 2;
  const int KS = (ws_size >= need8) ? 8 : 4;

  float* partial = (float*)d_ws;
  unsigned short* wh = (unsigned short*)((char*)d_ws +
                        (size_t)KS * T_TOK * NEXP * sizeof(float));
  unsigned short* wm = wh + WHALF;
  unsigned short* wl = wm + WHALF;

  hipLaunchKernelGGL(w_convert3, dim3(256), dim3(256), 0, stream, w, wh, wm, wl);
  if (KS == 8) {
    hipLaunchKernelGGL((router_gemm<8>), dim3((T_TOK / 32) * 8 / 4), dim3(256),
                       0, stream, x, wh, wm, wl, partial);
    hipLaunchKernelGGL((router_topk<8>), dim3(T_TOK / 32), dim3(256),
                       0, stream, partial, logits, scores, idxo);
  } else {
    hipLaunchKernelGGL((router_gemm<4>), dim3((T_TOK / 32) * 4 / 4), dim3(256),
                       0, stream, x, wh, wm, wl, partial);
    hipLaunchKernelGGL((router_topk<4>), dim3(T_TOK / 32), dim3(256),
                       0, stream, partial, logits, scores, idxo);
  }
}